// Round 9
// baseline (371.796 us; speedup 1.0000x reference)
//
#include <hip/hip_runtime.h>
#include <hip/hip_bf16.h>

#define DMODEL 1024
#define NH 16
#define DKH 64
#define NB 4
#define SEQ 2048
#define MTOT (NB*SEQ)   // 8192

typedef __bf16 bf16_t;
typedef __bf16 bf16x8 __attribute__((ext_vector_type(8)));
typedef float f32x4 __attribute__((ext_vector_type(4)));

__device__ __forceinline__ void async_copy16(void* lds, const void* g) {
    __builtin_amdgcn_global_load_lds(
        (const __attribute__((address_space(1))) unsigned int*)g,
        (__attribute__((address_space(3))) unsigned int*)lds, 16, 0, 0);
}

__device__ __forceinline__ float fast_exp2(float x) {
    return __builtin_amdgcn_exp2f(x);
}

__device__ __forceinline__ float rsum16(float v) {
    v += __shfl_xor(v, 1);
    v += __shfl_xor(v, 2);
    v += __shfl_xor(v, 4);
    v += __shfl_xor(v, 8);
    return v;
}

// fp32 -> bf16 elementwise; WEIGHTS ONLY now (activations converted in-GEMM).
__global__ void cvt_kernel(const float* __restrict__ s0, const float* __restrict__ s1,
                           const float* __restrict__ s2, const float* __restrict__ s3,
                           bf16_t* __restrict__ d0, bf16_t* __restrict__ d1,
                           bf16_t* __restrict__ d2, bf16_t* __restrict__ d3, int n)
{
    const float* s = (blockIdx.y == 0) ? s0 : (blockIdx.y == 1) ? s1 :
                     (blockIdx.y == 2) ? s2 : s3;
    bf16_t* d = (blockIdx.y == 0) ? d0 : (blockIdx.y == 1) ? d1 :
                (blockIdx.y == 2) ? d2 : d3;
    int i = (blockIdx.x * 256 + threadIdx.x) * 8;
    if (i < n) {
        float4 a = *(const float4*)&s[i];
        float4 b = *(const float4*)&s[i + 4];
        union { bf16_t h[8]; uint4 u; } t;
        t.h[0]=(bf16_t)a.x; t.h[1]=(bf16_t)a.y; t.h[2]=(bf16_t)a.z; t.h[3]=(bf16_t)a.w;
        t.h[4]=(bf16_t)b.x; t.h[5]=(bf16_t)b.y; t.h[6]=(bf16_t)b.z; t.h[7]=(bf16_t)b.w;
        *(uint4*)&d[i] = t.u;
    }
}

// Fused Q/K/V projection, ROUND 9: A-side reads fp32 activations DIRECTLY
// via global_load_lds (16B = 4 fp32) into a 32KB fp32 LDS tile; conversion
// to bf16 happens at fragment-read time (compiler emits cvt_pk). This
// deletes the 144MB activation cvt pass. NOT the R3 failure: R3 reg-staged
// (m151 anti-pattern); this keeps the async-LDS path. LDS 32+16=48KB ->
// still 3 blocks/CU. A-frag reads at row-stride 256B would be 16-way bank
// conflicts, so A gets the rule-#21 swizzle over 16 chunks (linear LDS dest,
// global source chunk ^= row&15, read chunk ^= row&15) -> 2-way (free).
// W path unchanged: bf16 from cvt, linear (its 16-way conflicts proven
// harmless in this barrier-bound regime, R5).
__global__ __launch_bounds__(256, 3)
void gemm_qkv(const float* __restrict__ Aq, const float* __restrict__ Ak,
              const float* __restrict__ Av, const bf16_t* __restrict__ W3,
              const float* __restrict__ bqp, const float* __restrict__ bkp,
              const float* __restrict__ bvp,
              bf16_t* __restrict__ Qh, bf16_t* __restrict__ Kh,
              bf16_t* __restrict__ Vth, float qscale)
{
    __shared__ __align__(16) float  Asf[128 * 64];   // 32 KB fp32
    __shared__ __align__(16) bf16_t Ws[128 * 64];    // 16 KB bf16

    const int tid  = threadIdx.x;
    const int wave = tid >> 6;
    const int lane = tid & 63;
    const int ln   = lane & 15;
    const int quad = lane >> 4;
    const int wm   = (wave >> 1) * 64;
    const int wn   = (wave & 1) * 64;
    const int bm   = blockIdx.x * 128;
    const int bnG  = blockIdx.y * 128;       // 0..3071 into packed W3
    const int sel  = blockIdx.y >> 3;        // 0=Q, 1=K, 2=V (block-uniform)
    const float* A32 = (sel == 0) ? Aq : (sel == 1) ? Ak : Av;
    // W staging (bf16): thread t -> row wave*8 + (lane>>3), chunk (lane&7)*8 elems
    const int srow = wave * 8 + (lane >> 3);
    const int sg   = (lane & 7) * 8;
    // A staging (fp32): 8 batches x 16 rows; thread t -> row t>>4, chunk t&15
    const int ar16 = tid >> 4;
    const int ac16 = tid & 15;

    f32x4 acc[4][4] = {};

    for (int k0 = 0; k0 < DMODEL; k0 += 64) {
        // A fp32: 8 x 4KB batches; LDS linear, source chunk inverse-swizzled
        #pragma unroll
        for (int b = 0; b < 8; ++b) {
            const int row = b * 16 + ar16;
            const int csr = ac16 ^ (row & 15);
            async_copy16(&Asf[(size_t)(b * 16 + wave * 4) * 64],
                         &A32[(size_t)(bm + row) * DMODEL + k0 + csr * 4]);
        }
        // W bf16: 4 x 4KB batches, linear
        #pragma unroll
        for (int rr = 0; rr < 4; ++rr) {
            const int row = rr * 32 + srow;
            async_copy16(&Ws[(size_t)(rr * 32 + wave * 8) * 64],
                         &W3[(size_t)(bnG + row) * DMODEL + k0 + sg]);
        }
        __syncthreads();   // drains vmcnt: tile resident

        #pragma unroll
        for (int h = 0; h < 2; ++h) {
            bf16x8 af[4], wf[4];
            #pragma unroll
            for (int u = 0; u < 4; ++u) {
                const int row = wm + u * 16 + ln;
                const int swz = row & 15;
                const int c0  = (h * 8 + quad * 2)     ^ swz;
                const int c1  = (h * 8 + quad * 2 + 1) ^ swz;
                f32x4 p0 = *(const f32x4*)&Asf[row * 64 + c0 * 4];
                f32x4 p1 = *(const f32x4*)&Asf[row * 64 + c1 * 4];
                bf16x8 t;
                t[0] = (bf16_t)p0[0]; t[1] = (bf16_t)p0[1];
                t[2] = (bf16_t)p0[2]; t[3] = (bf16_t)p0[3];
                t[4] = (bf16_t)p1[0]; t[5] = (bf16_t)p1[1];
                t[6] = (bf16_t)p1[2]; t[7] = (bf16_t)p1[3];
                af[u] = t;
                wf[u] = *(const bf16x8*)&Ws[(wn + u * 16 + ln) * 64 + h * 32 + quad * 8];
            }
            #pragma unroll
            for (int im = 0; im < 4; ++im)
                #pragma unroll
                for (int jn = 0; jn < 4; ++jn)
                    acc[im][jn] = __builtin_amdgcn_mfma_f32_16x16x32_bf16(
                        af[im], wf[jn], acc[im][jn], 0, 0, 0);
        }
        __syncthreads();
    }

    const float* bias = (sel == 0) ? bqp : (sel == 1) ? bkp : bvp;
    const float scale = (sel == 0) ? qscale : 1.0f;
    const int bn = bnG & (DMODEL - 1);       // col within the selected 1024

    #pragma unroll
    for (int jn = 0; jn < 4; ++jn) {
        int n = bn + wn + jn * 16 + ln;
        float bv = bias[n];
        int h = n >> 6, d = n & 63;
        #pragma unroll
        for (int im = 0; im < 4; ++im) {
            #pragma unroll
            for (int r = 0; r < 4; ++r) {
                int m = bm + wm + im * 16 + quad * 4 + r;
                float v = (acc[im][jn][r] + bv) * scale;
                int b = m >> 11, s = m & (SEQ - 1);
                if (sel == 2) {
                    Vth[(((size_t)(b * NH + h)) * DKH + d) * SEQ + s] = (bf16_t)v;
                } else {
                    bf16_t* outp = (sel == 1) ? Kh : Qh;
                    outp[(((size_t)(b * NH + h)) * SEQ + s) * DKH + d] = (bf16_t)v;
                }
            }
        }
    }
}

// Output projection, ROUND 9: 64x128 tile (was 128x128) -> grid 1024 blocks
// = 4 blocks/CU (was 512 = 2/CU, our least latency-hidden kernel at 256 TF).
// R5 proved staged-bytes-per-MFMA is not the limiter in this regime; R1
// proved resident-wave count is. LDS 8+16=24KB; VGPR ~60 << 128 cap from
// launch_bounds(256,4) (cap safely above need - R3 spill lesson).
// fp32 row-major out[m*N + n].
__global__ __launch_bounds__(256, 4)
void gemm_o(const bf16_t* __restrict__ A, const bf16_t* __restrict__ W,
            const float* __restrict__ bias, float* __restrict__ out)
{
    __shared__ bf16_t As[64 * 64];     // 8 KB
    __shared__ bf16_t Ws[128 * 64];    // 16 KB

    const int tid  = threadIdx.x;
    const int wave = tid >> 6;
    const int lane = tid & 63;
    const int ln   = lane & 15;
    const int quad = lane >> 4;
    const int wm   = (wave >> 1) * 32;   // 0,32
    const int wn   = (wave & 1) * 64;    // 0,64
    const int bm   = blockIdx.x * 64;
    const int bn   = blockIdx.y * 128;
    // A staging: 2 batches x 32 rows; thread t -> row t>>3, chunk t&7
    const int ar   = tid >> 3;
    const int ac   = (tid & 7) * 8;
    // W staging: as gemm_qkv
    const int srow = wave * 8 + (lane >> 3);
    const int sg   = (lane & 7) * 8;

    f32x4 acc[2][4] = {};

    for (int k0 = 0; k0 < DMODEL; k0 += 64) {
        #pragma unroll
        for (int b2 = 0; b2 < 2; ++b2) {
            const int row = b2 * 32 + ar;
            async_copy16(&As[(size_t)(b2 * 32 + wave * 8) * 64],
                         &A[(size_t)(bm + row) * DMODEL + k0 + ac]);
        }
        #pragma unroll
        for (int rr = 0; rr < 4; ++rr) {
            const int row = rr * 32 + srow;
            async_copy16(&Ws[(size_t)(rr * 32 + wave * 8) * 64],
                         &W[(size_t)(bn + row) * DMODEL + k0 + sg]);
        }
        __syncthreads();   // drains vmcnt: tile resident

        bf16x8 af[2][2], wf[2][4];
        #pragma unroll
        for (int h = 0; h < 2; ++h) {
            #pragma unroll
            for (int u = 0; u < 2; ++u)
                af[h][u] = *(const bf16x8*)&As[(wm + u * 16 + ln) * 64 + h * 32 + quad * 8];
            #pragma unroll
            for (int u = 0; u < 4; ++u)
                wf[h][u] = *(const bf16x8*)&Ws[(wn + u * 16 + ln) * 64 + h * 32 + quad * 8];
        }
        #pragma unroll
        for (int h = 0; h < 2; ++h)
            #pragma unroll
            for (int im = 0; im < 2; ++im)
                #pragma unroll
                for (int jn = 0; jn < 4; ++jn)
                    acc[im][jn] = __builtin_amdgcn_mfma_f32_16x16x32_bf16(
                        af[h][im], wf[h][jn], acc[im][jn], 0, 0, 0);

        __syncthreads();
    }

    #pragma unroll
    for (int jn = 0; jn < 4; ++jn) {
        const int n = bn + wn + jn * 16 + ln;
        const float bv = bias[n];
        #pragma unroll
        for (int im = 0; im < 2; ++im) {
            #pragma unroll
            for (int r = 0; r < 4; ++r) {
                const int m = bm + wm + im * 16 + quad * 4 + r;
                out[(size_t)m * DMODEL + n] = acc[im][jn][r] + bv;
            }
        }
    }
}

// Flash attention, causal, NO-MAX softmax, COMPLEMENTARY Q-TILE PAIRING —
// exact R4/R8 version (best measured). UNCHANGED this round.
__global__ __launch_bounds__(256, 2)
void attn_kernel(const bf16_t* __restrict__ Q, const bf16_t* __restrict__ Km,
                 const bf16_t* __restrict__ Vt, bf16_t* __restrict__ X)
{
    __shared__ __align__(16) bf16_t Ks[2][64 * 64];
    __shared__ __align__(16) bf16_t Vs[2][64 * 64];
    __shared__ __align__(16) bf16_t Ps[4][32][72];

    const int tid  = threadIdx.x;
    const int wave = tid >> 6;
    const int lane = tid & 63;
    const int ln   = lane & 15;
    const int quad = lane >> 4;
    const int cs   = ln & 7;              // read-side swizzle key (= row & 7)

    const int bh  = blockIdx.x;           // bh-fast -> same XCD per bh
    const int qtA = blockIdx.y;           // 0..7
    const int qtB = 15 - qtA;
    const int q0A = qtA * 128;
    const int q0B = qtB * 128;
    const size_t base = (size_t)bh * SEQ * DKH;

    // 4 strips of 16 rows per wave: s0=q0A, s1=q0A+64, s2=q0B, s3=q0B+64
    bf16x8 aq[4][2];
    #pragma unroll
    for (int st = 0; st < 4; ++st) {
        const int sb = ((st < 2) ? q0A : q0B) + (st & 1) * 64;
        const bf16_t* qr = Q + base + (size_t)(sb + wave * 16 + ln) * DKH;
        aq[st][0] = *(const bf16x8*)(qr + quad * 8);
        aq[st][1] = *(const bf16x8*)(qr + 32 + quad * 8);
    }

    f32x4 oacc[4][4] = {};
    float psum[4][4] = {};

    const int nkt = 2 * qtB + 2;          // key tiles for the LATE Q-tile

    const int srow8 = lane >> 3;
    const int schk  = lane & 7;

    // prologue: stage tile 0 into buffer 0
    #pragma unroll
    for (int qq = 0; qq < 2; ++qq) {
        const int rb  = wave * 16 + qq * 8;
        const int row = rb + srow8;
        const int csr = schk ^ (row & 7);
        async_copy16(&Ks[0][rb * 64], Km + base + (size_t)row * DKH + csr * 8);
        async_copy16(&Vs[0][rb * 64], Vt + base + (size_t)row * SEQ + csr * 8);
    }
    __syncthreads();   // drain: buffer 0 resident

    int cur = 0;
    for (int kt = 0; kt < nkt; ++kt, cur ^= 1) {
        const int j0 = kt * 64;

        // issue next tile's staging first: in flight across the whole compute
        if (kt + 1 < nkt) {
            const int jn0 = j0 + 64;
            #pragma unroll
            for (int qq = 0; qq < 2; ++qq) {
                const int rb  = wave * 16 + qq * 8;
                const int row = rb + srow8;
                const int csr = schk ^ (row & 7);
                async_copy16(&Ks[cur ^ 1][rb * 64],
                             Km + base + (size_t)(jn0 + row) * DKH + csr * 8);
                async_copy16(&Vs[cur ^ 1][rb * 64],
                             Vt + base + (size_t)row * SEQ + jn0 + csr * 8);
            }
        }

        bf16x8 kf[4][2];
        #pragma unroll
        for (int jn = 0; jn < 4; ++jn) {
            const int rr = (jn * 16 + ln) * 64;
            kf[jn][0] = *(const bf16x8*)&Ks[cur][rr + ((quad    ) ^ cs) * 8];
            kf[jn][1] = *(const bf16x8*)&Ks[cur][rr + ((4 + quad) ^ cs) * 8];
        }
        bf16x8 vf[4][2];
        #pragma unroll
        for (int nj = 0; nj < 4; ++nj) {
            const int rr = (nj * 16 + ln) * 64;
            vf[nj][0] = *(const bf16x8*)&Vs[cur][rr + ((quad    ) ^ cs) * 8];
            vf[nj][1] = *(const bf16x8*)&Vs[cur][rr + ((4 + quad) ^ cs) * 8];
        }

        // strip pairs {0,1} (Q-tile A) and {2,3} (Q-tile B)
        #pragma unroll
        for (int pair = 0; pair < 2; ++pair) {
            const int q0p = (pair == 0) ? q0A : q0B;

            f32x4 s[2][4] = {};
            #pragma unroll
            for (int sl = 0; sl < 2; ++sl) {
                const int st = pair * 2 + sl;
                const int sb = q0p + sl * 64;
                if (j0 > sb + 63) continue;       // strip fully masked (uniform)
                #pragma unroll
                for (int jn = 0; jn < 4; ++jn) {
                    s[sl][jn] = __builtin_amdgcn_mfma_f32_16x16x32_bf16(aq[st][0], kf[jn][0], s[sl][jn], 0, 0, 0);
                    s[sl][jn] = __builtin_amdgcn_mfma_f32_16x16x32_bf16(aq[st][1], kf[jn][1], s[sl][jn], 0, 0, 0);
                }
            }

            #pragma unroll
            for (int sl = 0; sl < 2; ++sl) {
                const int st = pair * 2 + sl;
                const int sb = q0p + sl * 64;
                if (j0 > sb + 63) continue;       // strip fully masked
                const int rbase = sb + wave * 16 + quad * 4;
                const bool diag = (j0 + 63 > sb);
                #pragma unroll
                for (int r = 0; r < 4; ++r) {
                    float rowsum = 0.f;
                    #pragma unroll
                    for (int jn = 0; jn < 4; ++jn) {
                        float v = s[sl][jn][r];
                        if (diag) {
                            int col = j0 + jn * 16 + ln;
                            if (col > rbase + r) v = -1e30f;
                        }
                        float p = fast_exp2(v);      // exp2(-1e30) == 0
                        s[sl][jn][r] = p;
                        rowsum += p;
                    }
                    psum[st][r] += rowsum;
                }
                #pragma unroll
                for (int r = 0; r < 4; ++r)
                    #pragma unroll
                    for (int jn = 0; jn < 4; ++jn)
                        Ps[wave][sl * 16 + quad * 4 + r][jn * 16 + ln] = (bf16_t)s[sl][jn][r];

                // O += P V (per-wave private LDS tile; same-wave order, no barrier)
                bf16x8 ap0 = *(const bf16x8*)&Ps[wave][sl * 16 + ln][quad * 8];
                bf16x8 ap1 = *(const bf16x8*)&Ps[wave][sl * 16 + ln][32 + quad * 8];
                #pragma unroll
                for (int nj = 0; nj < 4; ++nj) {
                    oacc[st][nj] = __builtin_amdgcn_mfma_f32_16x16x32_bf16(ap0, vf[nj][0], oacc[st][nj], 0, 0, 0);
                    oacc[st][nj] = __builtin_amdgcn_mfma_f32_16x16x32_bf16(ap1, vf[nj][1], oacc[st][nj], 0, 0, 0);
                }
            }
        }

        // one barrier per tile: drains next-tile staging (vmcnt) and orders
        // this tile's LDS reads before buffer reuse (lgkmcnt)
        __syncthreads();
    }

    const int bb = bh >> 4, hh = bh & 15;
    #pragma unroll
    for (int st = 0; st < 4; ++st) {
        const int sb = ((st < 2) ? q0A : q0B) + (st & 1) * 64;
        #pragma unroll
        for (int r = 0; r < 4; ++r) {
            int sg = sb + wave * 16 + quad * 4 + r;
            float inv = 1.f / rsum16(psum[st][r]);
            #pragma unroll
            for (int nj = 0; nj < 4; ++nj)
                X[((size_t)(bb * SEQ + sg)) * DMODEL + hh * DKH + nj * 16 + ln] =
                    (bf16_t)(oacc[st][nj][r] * inv);
        }
    }
}

extern "C" void kernel_launch(void* const* d_in, const int* in_sizes, int n_in,
                              void* d_out, int out_size, void* d_ws, size_t ws_size,
                              hipStream_t stream)
{
    const float* query = (const float*)d_in[0];
    const float* key   = (const float*)d_in[1];
    const float* value = (const float*)d_in[2];
    const float* Wq = (const float*)d_in[4];
    const float* bq = (const float*)d_in[5];
    const float* Wk = (const float*)d_in[6];
    const float* bk = (const float*)d_in[7];
    const float* Wv = (const float*)d_in[8];
    const float* bv = (const float*)d_in[9];
    const float* Wo = (const float*)d_in[10];
    const float* bo = (const float*)d_in[11];
    float* out = (float*)d_out;

    // Buffer plan (ws 72 MB + d_out 32 MB used as scratch):
    //  ws[0,16)   X    (attn output, bf16)
    //  ws[48,64)  Qh
    //  ws[64,70)  Wqb|Wkb|Wvb  (contiguous 3072x1024 packed W3)
    //  ws[70,72)  Wob
    //  d_out[0,16)  Kh   (scratch; dead before gemm_o writes out)
    //  d_out[16,32) Vth  (scratch; dead before gemm_o writes out)
    // Activations are read fp32 directly by gemm_qkv (no activation cvt).
    char* ws = (char*)d_ws;
    bf16_t* X   = (bf16_t*)(ws);
    bf16_t* Qh  = (bf16_t*)(ws + ((size_t)48 << 20));
    bf16_t* Wqb = (bf16_t*)(ws + ((size_t)64 << 20));
    bf16_t* Wkb = (bf16_t*)(ws + ((size_t)66 << 20));
    bf16_t* Wvb = (bf16_t*)(ws + ((size_t)68 << 20));
    bf16_t* Wob = (bf16_t*)(ws + ((size_t)70 << 20));
    bf16_t* Kh  = (bf16_t*)d_out;
    bf16_t* Vth = (bf16_t*)((char*)d_out + ((size_t)16 << 20));

    const int nW = DMODEL * DMODEL;
    cvt_kernel<<<dim3(nW / 2048, 4), 256, 0, stream>>>(Wq, Wk, Wv, Wo,
                                                       Wqb, Wkb, Wvb, Wob, nW);

    dim3 bt(256);
    const float qscale = 0.125f * 1.4426950408889634f;  // 1/sqrt(dk) * log2(e)

    gemm_qkv<<<dim3(MTOT / 128, 3 * DMODEL / 128), bt, 0, stream>>>(
        query, key, value, Wqb, bq, bk, bv, Qh, Kh, Vth, qscale);

    // bh-fast grid: 64 x 8 (complementary Q-tile pairing inside)
    attn_kernel<<<dim3(NB * NH, SEQ / 256), bt, 0, stream>>>(Qh, Kh, Vth, X);

    // output projection: 64x128 tile, grid (128, 8) = 1024 blocks, 4/CU
    gemm_o<<<dim3(MTOT / 64, DMODEL / 128), bt, 0, stream>>>(X, Wob, bo, out);
}